// Round 2
// baseline (3890.511 us; speedup 1.0000x reference)
//
#include <hip/hip_runtime.h>
#include <cmath>

// PolicyStep: B=4 T=2048 V=8192 D=512 NOPS=8 HID=1024 POL_OUT=1032
// Round 2: all-f32 I/O (reference arrays are float32; round-1 NaN came from
// misreading f32 as bf16). fp32 VALU GEMM baseline, float4 global loads,
// lifetime-aliased workspace (~135 MB).

namespace {

constexpr int Bb = 4, Tt = 2048, Vv = 8192, Dd = 512, HID = 1024, PO = 1032;
constexpr int NTOK = Bb * Tt; // 8192

enum { EPI_STORE = 0, EPI_DECAY = 1, EPI_ACCUM = 2, EPI_BIAS_GELU = 3, EPI_BIAS = 4, EPI_OUT = 5 };

// C[M,N] = epilogue( sum_k A[m,k] * (BT ? B[n,k] : B[k,n]) )
// 64x64 tile, 256 threads, 4x4 micro-tile, K-tile 16. LDS K-major (As[k][m]).
template <bool BT, int EPI, bool SKIPK, bool NGUARD>
__launch_bounds__(256)
__global__ void gemm_kernel(int M, int N, int K,
                            const float* __restrict__ A, int lda, long long sAz,
                            const float* __restrict__ B, int ldb, long long sBz,
                            float* __restrict__ C, int ldc, long long sCz,
                            const float* __restrict__ rowScale,
                            const float* __restrict__ bias,
                            const float* __restrict__ scale_ptr,
                            const float* __restrict__ decayPow) {
  const int bx = blockIdx.x, by = blockIdx.y, bz = blockIdx.z;
  if (EPI == EPI_DECAY) {
    if (bx < by) return; // whole tile has j<=i => w==0, never read downstream
  }
  __shared__ float As[16][68];
  __shared__ float Bs[16][68];
  A += (long long)bz * sAz;
  B += (long long)bz * sBz;
  const int tid = threadIdx.x;
  const int tx = tid & 15, ty = tid >> 4;
  float acc[4][4] = {};
  const int k0 = SKIPK ? by * 64 : 0; // mem GEMM: cols j < by*64 are all-zero
  const int ar = tid >> 2;      // 0..63 row within tile
  const int ac = (tid & 3) * 4; // 0,4,8,12 k within tile
  float ascale = 1.0f;
  if (rowScale) ascale = rowScale[by * 64 + ar];
  for (int kt = k0; kt < K; kt += 16) {
    { // A tile (rows of A), store K-major
      const float4 av = *reinterpret_cast<const float4*>(
          A + (long long)(by * 64 + ar) * lda + (kt + ac));
      As[ac + 0][ar] = av.x * ascale;
      As[ac + 1][ar] = av.y * ascale;
      As[ac + 2][ar] = av.z * ascale;
      As[ac + 3][ar] = av.w * ascale;
    }
    if (BT) {
      const int n = bx * 64 + ar;
      if (!NGUARD || n < N) {
        const float4 bv = *reinterpret_cast<const float4*>(
            B + (long long)n * ldb + (kt + ac));
        Bs[ac + 0][ar] = bv.x; Bs[ac + 1][ar] = bv.y;
        Bs[ac + 2][ar] = bv.z; Bs[ac + 3][ar] = bv.w;
      } else {
        Bs[ac + 0][ar] = 0.0f; Bs[ac + 1][ar] = 0.0f;
        Bs[ac + 2][ar] = 0.0f; Bs[ac + 3][ar] = 0.0f;
      }
    } else { // B[k,n]: coalesce along n
      const int nloc = tid & 63, kb = (tid >> 6) * 4;
#pragma unroll
      for (int u = 0; u < 4; ++u)
        Bs[kb + u][nloc] = B[(long long)(kt + kb + u) * ldb + (bx * 64 + nloc)];
    }
    __syncthreads();
#pragma unroll
    for (int kk = 0; kk < 16; ++kk) {
      float a0[4], b0[4];
#pragma unroll
      for (int i = 0; i < 4; ++i) a0[i] = As[kk][ty * 4 + i];
#pragma unroll
      for (int j = 0; j < 4; ++j) b0[j] = Bs[kk][tx * 4 + j];
#pragma unroll
      for (int i = 0; i < 4; ++i)
#pragma unroll
        for (int j = 0; j < 4; ++j) acc[i][j] += a0[i] * b0[j];
    }
    __syncthreads();
  }
  const int row0 = by * 64 + ty * 4;
  const int col0 = bx * 64 + tx * 4;
  float scl = 1.0f;
  if (EPI == EPI_ACCUM || EPI == EPI_OUT) scl = *scale_ptr;
#pragma unroll
  for (int i = 0; i < 4; ++i) {
#pragma unroll
    for (int j = 0; j < 4; ++j) {
      const int r = row0 + i, c = col0 + j;
      if (NGUARD && c >= N) continue;
      const long long idx = (long long)bz * sCz + (long long)r * ldc + c;
      float v = acc[i][j];
      if (EPI == EPI_STORE) {
        C[idx] = v;
      } else if (EPI == EPI_DECAY) {
        const int d = c - r;
        C[idx] = (d > 0) ? v * decayPow[d - 1] : 0.0f;
      } else if (EPI == EPI_ACCUM) {
        C[idx] += scl * v; // h += mem_scale * mem
      } else if (EPI == EPI_BIAS_GELU) {
        float t = v + bias[c];
        C[idx] = 0.5f * t * (1.0f + erff(t * 0.70710678118654752440f));
      } else if (EPI == EPI_BIAS) {
        C[idx] = v + bias[c];
      } else { // EPI_OUT
        C[idx] = v * scl;
      }
    }
  }
}

__global__ void decaypow_kernel(const float* __restrict__ decay_logit,
                                float* __restrict__ pw) {
  const int e = blockIdx.x * 256 + threadIdx.x;
  if (e < Tt) {
    const float decay = 1.0f / (1.0f + expf(-*decay_logit));
    pw[e] = powf(decay, (float)e);
  }
}

__global__ void rmsnorm_kernel(const float* __restrict__ x,
                               float* __restrict__ rstd) {
  const int t = blockIdx.x, tid = threadIdx.x;
  const float4* xr = reinterpret_cast<const float4*>(x + (long long)t * Vv);
  float s = 0.0f;
  for (int i = tid; i < Vv / 4; i += 256) {
    const float4 v = xr[i];
    s += v.x * v.x + v.y * v.y + v.z * v.z + v.w * v.w;
  }
  __shared__ float red[256];
  red[tid] = s;
  __syncthreads();
  for (int st = 128; st > 0; st >>= 1) {
    if (tid < st) red[tid] += red[tid + st];
    __syncthreads();
  }
  if (tid == 0) rstd[t] = rsqrtf(red[0] / (float)Vv + 1.1920929e-07f);
}

// per-token: read_w=softmax(pol[:512]) -> sel=h*read_w; op_w=softmax(pol[512:520]);
// write_w=sigmoid(pol[520:]) in place.
__global__ void policy_kernel(float* __restrict__ pol, const float* __restrict__ h,
                              float* __restrict__ sel, float* __restrict__ opw) {
  const int t = blockIdx.x, tid = threadIdx.x;
  float* prow = pol + (long long)t * PO;
  __shared__ float red[256];
  const float v0 = prow[tid], v1 = prow[tid + 256];
  red[tid] = fmaxf(v0, v1);
  __syncthreads();
  for (int s = 128; s > 0; s >>= 1) {
    if (tid < s) red[tid] = fmaxf(red[tid], red[tid + s]);
    __syncthreads();
  }
  const float mx = red[0];
  __syncthreads();
  const float e0 = expf(v0 - mx), e1 = expf(v1 - mx);
  red[tid] = e0 + e1;
  __syncthreads();
  for (int s = 128; s > 0; s >>= 1) {
    if (tid < s) red[tid] += red[tid + s];
    __syncthreads();
  }
  const float inv = 1.0f / red[0];
  const float* hrow = h + (long long)t * Dd;
  sel[(long long)t * Dd + tid] = hrow[tid] * e0 * inv;
  sel[(long long)t * Dd + tid + 256] = hrow[tid + 256] * e1 * inv;
  if (tid == 0) {
    float ov[8];
    float om = -1e30f;
    for (int n = 0; n < 8; ++n) { ov[n] = prow[512 + n]; om = fmaxf(om, ov[n]); }
    float osum = 0.0f;
    for (int n = 0; n < 8; ++n) { ov[n] = expf(ov[n] - om); osum += ov[n]; }
    const float oi = 1.0f / osum;
    for (int n = 0; n < 8; ++n) opw[(long long)t * 8 + n] = ov[n] * oi;
  }
  const float w0 = prow[520 + tid];
  prow[520 + tid] = 1.0f / (1.0f + expf(-w0));
  const float w1 = prow[520 + 256 + tid];
  prow[520 + 256 + tid] = 1.0f / (1.0f + expf(-w1));
}

// result[t,e] = write_w[t,e] * sum_n opw[t,n] * act_n( sum_d sel[t,d]*Wops[n,e,d] )
__launch_bounds__(256)
__global__ void opbank_kernel(const float* __restrict__ sel,
                              const float* __restrict__ Wops,
                              const float* __restrict__ opw,
                              const float* __restrict__ pol,
                              float* __restrict__ result) {
  const int bx = blockIdx.x, by = blockIdx.y;
  __shared__ float As[16][68];
  __shared__ float Bs[16][68];
  const int tid = threadIdx.x;
  const int tx = tid & 15, ty = tid >> 4;
  const int ar = tid >> 2, ac = (tid & 3) * 4;
  float res[4][4] = {};
  for (int n = 0; n < 8; ++n) {
    float acc[4][4] = {};
    const float* Wn = Wops + (long long)n * Dd * Dd;
    for (int kt = 0; kt < Dd; kt += 16) {
      const float4 av = *reinterpret_cast<const float4*>(
          sel + (long long)(by * 64 + ar) * Dd + (kt + ac));
      As[ac + 0][ar] = av.x; As[ac + 1][ar] = av.y;
      As[ac + 2][ar] = av.z; As[ac + 3][ar] = av.w;
      const float4 bv = *reinterpret_cast<const float4*>(
          Wn + (long long)(bx * 64 + ar) * Dd + (kt + ac));
      Bs[ac + 0][ar] = bv.x; Bs[ac + 1][ar] = bv.y;
      Bs[ac + 2][ar] = bv.z; Bs[ac + 3][ar] = bv.w;
      __syncthreads();
#pragma unroll
      for (int kk = 0; kk < 16; ++kk) {
        float a0[4], b0[4];
#pragma unroll
        for (int i = 0; i < 4; ++i) a0[i] = As[kk][ty * 4 + i];
#pragma unroll
        for (int j = 0; j < 4; ++j) b0[j] = Bs[kk][tx * 4 + j];
#pragma unroll
        for (int i = 0; i < 4; ++i)
#pragma unroll
          for (int j = 0; j < 4; ++j) acc[i][j] += a0[i] * b0[j];
      }
      __syncthreads();
    }
#pragma unroll
    for (int i = 0; i < 4; ++i) {
      const float ow = opw[(long long)(by * 64 + ty * 4 + i) * 8 + n];
#pragma unroll
      for (int j = 0; j < 4; ++j) {
        const float hv = acc[i][j];
        float av;
        switch (n) {
          case 0: av = 0.5f * hv * (1.0f + erff(hv * 0.70710678118654752440f)); break;
          case 1: av = fmaxf(hv, 0.0f); break;
          case 2: { const float r_ = fmaxf(hv, 0.0f); av = r_ * r_; } break;
          case 3: av = hv / (1.0f + expf(-hv)); break;
          case 4: av = tanhf(hv); break;
          case 5: av = 1.0f / (1.0f + expf(-hv)); break;
          case 6: av = hv; break;
          default: av = -hv; break;
        }
        res[i][j] += ow * av;
      }
    }
  }
#pragma unroll
  for (int i = 0; i < 4; ++i) {
#pragma unroll
    for (int j = 0; j < 4; ++j) {
      const int t = by * 64 + ty * 4 + i, e = bx * 64 + tx * 4 + j;
      const float ww = pol[(long long)t * PO + 520 + e];
      result[(long long)t * Dd + e] = res[i][j] * ww;
    }
  }
}

} // namespace

extern "C" void kernel_launch(void* const* d_in, const int* in_sizes, int n_in,
                              void* d_out, int out_size, void* d_ws, size_t ws_size,
                              hipStream_t stream) {
  const float* x    = (const float*)d_in[0];
  const float* Wc   = (const float*)d_in[1];
  const float* We   = (const float*)d_in[2];
  const float* Wq   = (const float*)d_in[3];
  const float* Wk   = (const float*)d_in[4];
  const float* Wv   = (const float*)d_in[5];
  const float* W1   = (const float*)d_in[6];
  const float* b1   = (const float*)d_in[7];
  const float* W2   = (const float*)d_in[8];
  const float* b2   = (const float*)d_in[9];
  const float* Wops = (const float*)d_in[10];
  const float* dlg  = (const float*)d_in[11];
  const float* msc  = (const float*)d_in[12];
  const float* asc  = (const float*)d_in[13];

  float* ws = (float*)d_ws;
  // lifetime-aliased layout (~135 MB):
  float* h      = ws;                         // 4,194,304
  float* q      = ws + 4194304;               // dead after scores -> sel
  float* k      = ws + 2 * 4194304;           // dead after scores -> result
  float* v      = ws + 3 * 4194304;           // dead after mem
  float* scores = ws + 4 * 4194304;           // 16,777,216; dead after mem
  float* a1     = scores;                     // 8,388,608 (reuse scores)
  float* pol    = scores + 8388608;           // 8,454,144
  float* sel    = q;                          // 4,194,304 (reuse q)
  float* result = k;                          // 4,194,304 (reuse k)
  float* rstd   = pol + 8454144;              // 8192
  float* dpw    = rstd + 8192;                // 2048
  float* opw    = dpw + 2048;                 // 65,536
  float* out    = (float*)d_out;

  decaypow_kernel<<<8, 256, 0, stream>>>(dlg, dpw);
  rmsnorm_kernel<<<NTOK, 256, 0, stream>>>(x, rstd);

  // h = (x * rstd) @ Wc^T   [8192 x 512 x 8192]
  gemm_kernel<true, EPI_STORE, false, false>
      <<<dim3(8, 128, 1), 256, 0, stream>>>(NTOK, Dd, Vv, x, Vv, 0, Wc, Vv, 0,
                                            h, Dd, 0, rstd, nullptr, nullptr, nullptr);
  // q,k,v = h @ W{q,k,v}^T  [8192 x 512 x 512]
  gemm_kernel<true, EPI_STORE, false, false>
      <<<dim3(8, 128, 1), 256, 0, stream>>>(NTOK, Dd, Dd, h, Dd, 0, Wq, Dd, 0,
                                            q, Dd, 0, nullptr, nullptr, nullptr, nullptr);
  gemm_kernel<true, EPI_STORE, false, false>
      <<<dim3(8, 128, 1), 256, 0, stream>>>(NTOK, Dd, Dd, h, Dd, 0, Wk, Dd, 0,
                                            k, Dd, 0, nullptr, nullptr, nullptr, nullptr);
  gemm_kernel<true, EPI_STORE, false, false>
      <<<dim3(8, 128, 1), 256, 0, stream>>>(NTOK, Dd, Dd, h, Dd, 0, Wv, Dd, 0,
                                            v, Dd, 0, nullptr, nullptr, nullptr, nullptr);
  // scores = (q @ k^T) * w  [per batch 2048 x 2048 x 512], lower-tri tiles skipped
  gemm_kernel<true, EPI_DECAY, false, false>
      <<<dim3(32, 32, 4), 256, 0, stream>>>(Tt, Tt, Dd, q, Dd, (long long)Tt * Dd,
                                            k, Dd, (long long)Tt * Dd,
                                            scores, Tt, (long long)Tt * Tt,
                                            nullptr, nullptr, nullptr, dpw);
  // h += mem_scale * (scores @ v)  [per batch 2048 x 512 x 2048], zero k-tiles skipped
  gemm_kernel<false, EPI_ACCUM, true, false>
      <<<dim3(8, 32, 4), 256, 0, stream>>>(Tt, Dd, Tt, scores, Tt, (long long)Tt * Tt,
                                           v, Dd, (long long)Tt * Dd,
                                           h, Dd, (long long)Tt * Dd,
                                           nullptr, nullptr, msc, nullptr);
  // a1 = gelu(h @ W1^T + b1)  [8192 x 1024 x 512]
  gemm_kernel<true, EPI_BIAS_GELU, false, false>
      <<<dim3(16, 128, 1), 256, 0, stream>>>(NTOK, HID, Dd, h, Dd, 0, W1, Dd, 0,
                                             a1, HID, 0, nullptr, b1, nullptr, nullptr);
  // pol = a1 @ W2^T + b2  [8192 x 1032 x 1024]
  gemm_kernel<true, EPI_BIAS, false, true>
      <<<dim3(17, 128, 1), 256, 0, stream>>>(NTOK, PO, HID, a1, HID, 0, W2, HID, 0,
                                             pol, PO, 0, nullptr, b2, nullptr, nullptr);
  policy_kernel<<<NTOK, 256, 0, stream>>>(pol, h, sel, opw);
  opbank_kernel<<<dim3(8, 128, 1), 256, 0, stream>>>(sel, Wops, opw, pol, result);
  // out = (result @ We^T) * act_scale  [8192 x 8192 x 512]
  gemm_kernel<true, EPI_OUT, false, false>
      <<<dim3(128, 128, 1), 256, 0, stream>>>(NTOK, Vv, Dd, result, Dd, 0, We, Dd, 0,
                                              out, Vv, 0, nullptr, nullptr, asc, nullptr);
}